// Round 1
// 324.616 us; speedup vs baseline: 1.0263x; 1.0263x over previous
//
#include <hip/hip_runtime.h>
#include <hip/hip_bf16.h>
#include <stdint.h>

typedef __bf16 bf16;
typedef unsigned char u8;
typedef bf16 bf16x4_t __attribute__((ext_vector_type(4)));
typedef bf16 bf16x8_t __attribute__((ext_vector_type(8)));
typedef float floatx4_t __attribute__((ext_vector_type(4)));

#define NB 8
#define SQ 2048
#define SKV 2048
#define DIN 512
#define DOUT 512

// scores = (q*4)(k*4)/16/sqrt(512): 1/(16*sqrt(512))
#define SCORE_SCALE 0.0027621358640099513f
// expS stored as e/16 to stay under fp8 e4m3 max (448)
#define P_STORE_SCALE 0.0625f
#define P_UNDO_SCALE 16.0f

__device__ __forceinline__ void load_lds16(const void* g, void* l) {
    __builtin_amdgcn_global_load_lds(
        (const __attribute__((address_space(1))) unsigned int*)g,
        (__attribute__((address_space(3))) unsigned int*)l, 16, 0, 0);
}

__device__ __forceinline__ u8 to_fp8(float f) {
    int v = __builtin_amdgcn_cvt_pk_fp8_f32(f, 0.f, 0, false);
    return (u8)(v & 0xff);
}
__device__ __forceinline__ unsigned int pack_fp8x4(float a, float b, float c, float d) {
    int lo = __builtin_amdgcn_cvt_pk_fp8_f32(a, b, 0, false);
    int all = __builtin_amdgcn_cvt_pk_fp8_f32(c, d, lo, true);
    return (unsigned int)all;
}

// 16-B-granule XOR swizzle within each 64-B k-block: breaks LDS bank aliasing
// for 8-B fp8 fragment reads. Producers write with it, LDS readers undo it.
// (64-B scope so a BK=64 double-buffered stage captures whole blocks.)
__device__ __forceinline__ int swz_off(int row, int col) {
    return (col & ~63) | ((((col >> 4) & 3) ^ (row & 3)) << 4) | (col & 15);
}

// ---------------- cast: query/key -> fp8(swz), value/offset/Woff -> bf16, zero l ----------------
struct CastArgs {
    const float* src[6];
    void* dst[6];
    int n4[6];
    int mode[6];  // 0=bf16, 1=fp8 swizzled (row len 512), 2=zero-f32
};
__global__ void cast_many(CastArgs a) {
    int z = blockIdx.z;
    int i = blockIdx.x * blockDim.x + threadIdx.x;
    if (i >= a.n4[z]) return;
    if (a.mode[z] == 2) {
        ((float4*)a.dst[z])[i] = make_float4(0.f, 0.f, 0.f, 0.f);
        return;
    }
    float4 f = ((const float4*)a.src[z])[i];
    if (a.mode[z] == 1) {
        int row = i >> 7;            // 128 float4-groups per 512-elem row
        int k0 = (i & 127) * 4;      // 4 bytes, within one 16-B granule
        u8* d = (u8*)a.dst[z];
        *(unsigned int*)&d[row * 512 + swz_off(row, k0)] = pack_fp8x4(f.x, f.y, f.z, f.w);
    } else {
        bf16x4_t o = { (bf16)f.x, (bf16)f.y, (bf16)f.z, (bf16)f.w };
        ((bf16x4_t*)a.dst[z])[i] = o;
    }
}

// ---------------- weight transpose f32[512,512] -> fp8(swz, x4) for Wq/Wk, bf16 for Wv ----------------
struct TWArgs { const float* src[3]; void* dst[3]; };
__global__ void transpose_w(TWArgs a) {
    __shared__ float t[32][33];
    const float* src = a.src[blockIdx.z];
    int tx = threadIdx.x, ty = threadIdx.y;
    int x0 = blockIdx.x * 32, y0 = blockIdx.y * 32;
#pragma unroll
    for (int j = 0; j < 4; ++j)
        t[ty + 8 * j][tx] = src[(y0 + ty + 8 * j) * DIN + x0 + tx];
    __syncthreads();
    if (blockIdx.z <= 1) {
        u8* d8 = (u8*)a.dst[blockIdx.z];
#pragma unroll
        for (int j = 0; j < 4; ++j) {
            int row = x0 + ty + 8 * j, col = y0 + tx;
            d8[row * 512 + swz_off(row, col)] = to_fp8(t[tx][ty + 8 * j] * 4.0f);
        }
    } else {
        bf16* db = (bf16*)a.dst[2];
#pragma unroll
        for (int j = 0; j < 4; ++j)
            db[(x0 + ty + 8 * j) * DIN + y0 + tx] = (bf16)t[tx][ty + 8 * j];
    }
}

// ---------------- bf16 NT mainloop, BK=32, double-buffered + pipelined ----------------
// Loads for step t+1 are issued BEFORE step t's compute; the single barrier per
// step (with its vmcnt drain) lands after the MFMAs, hiding global latency.
__device__ __forceinline__ void gemm_mainloop(
    floatx4_t (&acc)[4][4], const bf16* __restrict__ Ap, const bf16* __restrict__ Bp,
    int lda, int ldb, int K, bf16* As, bf16* Bs, int wave, int lane)
{
    const int wm = (wave & 1) * 64, wn = (wave >> 1) * 64;
    const int lm = lane & 15, quad = lane >> 4;
    const int srow = lane >> 2, scol = (lane & 3) * 8;

    auto STAGE = [&](int buf, int k0) {
#pragma unroll
        for (int t = 0; t < 2; ++t) {
            const int r0 = (wave * 2 + t) * 16;
            load_lds16(Ap + (long long)(r0 + srow) * lda + (k0 + scol),
                       &As[buf * 4096 + r0 * 32]);
            load_lds16(Bp + (long long)(r0 + srow) * ldb + (k0 + scol),
                       &Bs[buf * 4096 + r0 * 32]);
        }
    };

    STAGE(0, 0);
    __syncthreads();
    int cur = 0;
    for (int k0 = 0; k0 < K; k0 += 32) {
        if (k0 + 32 < K) STAGE(cur ^ 1, k0 + 32);
        bf16x8_t af[4], bfr[4];
#pragma unroll
        for (int i = 0; i < 4; ++i)
            af[i] = *(const bf16x8_t*)&As[cur * 4096 + (wm + i * 16 + lm) * 32 + quad * 8];
#pragma unroll
        for (int i = 0; i < 4; ++i)
            bfr[i] = *(const bf16x8_t*)&Bs[cur * 4096 + (wn + i * 16 + lm) * 32 + quad * 8];
#pragma unroll
        for (int i = 0; i < 4; ++i)
#pragma unroll
            for (int j = 0; j < 4; ++j)
                acc[i][j] = __builtin_amdgcn_mfma_f32_16x16x32_bf16(af[i], bfr[j], acc[i][j], 0, 0, 0);
        __syncthreads();
        cur ^= 1;
    }
}

// ---------------- fp8 NT mainloop, BK=64, double-buffered + pipelined ----------------
// A/B rows are 64-B-blocked with 16-B granule XOR(row&3) swizzle.
__device__ __forceinline__ void gemm_mainloop_fp8(
    floatx4_t (&acc)[4][4], const u8* __restrict__ Ap, const u8* __restrict__ Bp,
    int lda, int ldb, int K, u8* As, u8* Bs, int wave, int lane)
{
    const int wm = (wave & 1) * 64, wn = (wave >> 1) * 64;
    const int lm = lane & 15, quad = lane >> 4;
    const int srow = lane >> 2, scol = (lane & 3) * 16;  // 16 rows x 64 B per inst
    const int x3 = lm & 3;
    const int inner = (quad & 1) * 8;
    const int gh = quad >> 1;

    auto STAGE = [&](int buf, int k0) {
#pragma unroll
        for (int t = 0; t < 2; ++t) {
            const int r0 = (wave * 2 + t) * 16;
            load_lds16(Ap + (long long)(r0 + srow) * lda + k0 + scol, &As[buf * 8192 + r0 * 64]);
            load_lds16(Bp + (long long)(r0 + srow) * ldb + k0 + scol, &Bs[buf * 8192 + r0 * 64]);
        }
    };

    STAGE(0, 0);
    __syncthreads();
    int cur = 0;
    for (int k0 = 0; k0 < K; k0 += 64) {
        if (k0 + 64 < K) STAGE(cur ^ 1, k0 + 64);
#pragma unroll
        for (int p = 0; p < 2; ++p) {
            const int gL = p * 2 + gh;
            const int koff = ((gL ^ x3) << 4) + inner;  // undo producer swizzle
            long long a[4], b[4];
#pragma unroll
            for (int i = 0; i < 4; ++i)
                a[i] = *(const long long*)&As[cur * 8192 + (wm + i * 16 + lm) * 64 + koff];
#pragma unroll
            for (int i = 0; i < 4; ++i)
                b[i] = *(const long long*)&Bs[cur * 8192 + (wn + i * 16 + lm) * 64 + koff];
#pragma unroll
            for (int i = 0; i < 4; ++i)
#pragma unroll
                for (int j = 0; j < 4; ++j)
                    acc[i][j] = __builtin_amdgcn_mfma_f32_16x16x32_fp8_fp8(a[i], b[j], acc[i][j], 0, 0, 0);
        }
        __syncthreads();
        cur ^= 1;
    }
}

// ---------------- phase 1: Q/K projections (fp8) + VT projection (bf16) ----------------
// ids [0,1024): fp8 Q/K proj. xcd=id%8, t=id/8, m=t%4, gg=xcd+8*(t/4): y=gg%128, z=gg/128
// ids [1024,1536): VT[d,kv] = sum_k WvT[d,k]*value[kv,k]; z=id2%8, ym=(id2/8)%4, xn=(id2/8)/4
__global__ __launch_bounds__(256) void proj_gemm(
    const u8* __restrict__ query8, const u8* __restrict__ key8,
    const u8* __restrict__ WqT8, const u8* __restrict__ WkT8,
    u8* __restrict__ Qb8, u8* __restrict__ Kb8,
    const bf16* __restrict__ valueb, const bf16* __restrict__ WvT,
    bf16* __restrict__ VT, u8* __restrict__ VT8)
{
    __shared__ __align__(16) u8 smem[32768];
    const int tid = threadIdx.x;
    const int wave = tid >> 6, lane = tid & 63;
    const int wm = (wave & 1) * 64, wn = (wave >> 1) * 64;
    const int lm = lane & 15, quad = lane >> 4;
    const int id = blockIdx.x;

    floatx4_t acc[4][4];
#pragma unroll
    for (int i = 0; i < 4; ++i)
#pragma unroll
        for (int j = 0; j < 4; ++j) acc[i][j] = 0.0f;

    if (id < 1024) {
        const int xcd = id & 7, t = id >> 3, m = t & 3;
        const int gg = xcd + 8 * (t >> 2);
        const int y = gg & 127, z = gg >> 7;
        const u8* Ap = (z ? key8 : query8) + (long long)y * 128 * DIN;
        const u8* Bp = (z ? WkT8 : WqT8) + (long long)m * 128 * DIN;
        gemm_mainloop_fp8(acc, Ap, Bp, DIN, DIN, DIN, smem, smem + 16384, wave, lane);
        u8* C = z ? Kb8 : Qb8;
#pragma unroll
        for (int i = 0; i < 4; ++i)
#pragma unroll
            for (int j = 0; j < 4; ++j) {
                const int row0 = y * 128 + wm + i * 16 + quad * 4;
                const int col = m * 128 + wn + j * 16 + lm;
#pragma unroll
                for (int r = 0; r < 4; ++r)
                    C[(long long)(row0 + r) * DOUT + swz_off(row0 + r, col)] = to_fp8(acc[i][j][r]);
            }
    } else {
        const int id2 = id - 1024;
        const int z = id2 & 7, r2 = id2 >> 3;
        const int ym = r2 & 3, xn = r2 >> 2;
        const bf16* Ap = WvT + (long long)ym * 128 * DIN;
        const bf16* Bp = valueb + (long long)z * (SKV * DIN) + (long long)xn * 128 * DIN;
        gemm_mainloop(acc, Ap, Bp, DIN, DIN, DIN, (bf16*)smem, (bf16*)(smem + 16384), wave, lane);
        bf16* C = VT + (long long)z * (DOUT * SKV);
        u8* C8 = VT8 + (long long)z * (DOUT * SKV);
#pragma unroll
        for (int i = 0; i < 4; ++i)
#pragma unroll
            for (int j = 0; j < 4; ++j) {
                const int row0 = ym * 128 + wm + i * 16 + quad * 4;
                const int col = xn * 128 + wn + j * 16 + lm;
#pragma unroll
                for (int r = 0; r < 4; ++r) {
                    float v = acc[i][j][r];
                    C[(long long)(row0 + r) * SKV + col] = (bf16)v;
                    C8[(long long)(row0 + r) * SKV + swz_off(row0 + r, col)] = to_fp8(v);
                }
            }
    }
}

// ---------------- G split-K2: G32h = (Woff @ V)^T partial, bf16 path ----------------
// grid 256: z=id%8, h=(id>>3)&1, x=(id>>4)&3, y=(id>>6)&3
__global__ __launch_bounds__(256) void g_gemm(
    const bf16* __restrict__ VT, const bf16* __restrict__ Woffb,
    float* __restrict__ G32a, float* __restrict__ G32b)
{
    __shared__ __align__(16) u8 smem[32768];
    const int tid = threadIdx.x;
    const int wave = tid >> 6, lane = tid & 63;
    const int id = blockIdx.x;
    const int z = id & 7, h = (id >> 3) & 1, x = (id >> 4) & 3, y = (id >> 6) & 3;

    floatx4_t acc[4][4];
#pragma unroll
    for (int i = 0; i < 4; ++i)
#pragma unroll
        for (int j = 0; j < 4; ++j) acc[i][j] = 0.0f;

    const bf16* Ap = VT + (long long)z * (DOUT * SKV) + (long long)y * 128 * SKV + h * 1024;
    const bf16* Bp = Woffb + (long long)x * 128 * SKV + h * 1024;
    gemm_mainloop(acc, Ap, Bp, SKV, SKV, 1024, (bf16*)smem, (bf16*)(smem + 16384), wave, lane);

    const int wm = (wave & 1) * 64, wn = (wave >> 1) * 64;
    const int lm = lane & 15, quad = lane >> 4;
    float* C = (h ? G32b : G32a) + (long long)z * (DOUT * DIN);
#pragma unroll
    for (int i = 0; i < 4; ++i)
#pragma unroll
        for (int j = 0; j < 4; ++j) {
            const int row0 = y * 128 + wm + i * 16 + quad * 4;
            const int col = x * 128 + wn + j * 16 + lm;
#pragma unroll
            for (int r = 0; r < 4; ++r)
                C[(long long)(row0 + r) * DIN + col] = acc[i][j][r];
        }
}

// ---------------- S-GEMM fp8 + exp epilogue + row sums; ids>=2048 convert G32->Gb ----------------
// grid 2112: s-blocks: z=id%8, x=(id/8)%16, y=(id/8)/16
__global__ __launch_bounds__(256) void s_gemm_exp(
    const u8* __restrict__ Qb8, const u8* __restrict__ Kb8,
    u8* __restrict__ expS8, float* __restrict__ l,
    const float* __restrict__ G32a, const float* __restrict__ G32b,
    bf16* __restrict__ Gb)
{
    __shared__ __align__(16) u8 smem[32768];
    const int tid = threadIdx.x;
    const int id = blockIdx.x;
    if (id >= 2048) {
        // convert G32a+G32b -> Gb (2M elems, 64 blocks x 256 thr x 32 float4)
        const int base = (id - 2048) * 256 + tid;
        const float4* A4 = (const float4*)G32a;
        const float4* B4 = (const float4*)G32b;
        bf16x4_t* O4 = (bf16x4_t*)Gb;
#pragma unroll 4
        for (int t = 0; t < 32; ++t) {
            const int idx = base + t * 16384;
            float4 a = A4[idx], b = B4[idx];
            bf16x4_t o = { (bf16)(a.x + b.x), (bf16)(a.y + b.y),
                           (bf16)(a.z + b.z), (bf16)(a.w + b.w) };
            O4[idx] = o;
        }
        return;
    }
    const int wave = tid >> 6, lane = tid & 63;
    const int z = id & 7, x = (id >> 3) & 15, y = (id >> 3) >> 4;

    floatx4_t acc[4][4];
#pragma unroll
    for (int i = 0; i < 4; ++i)
#pragma unroll
        for (int j = 0; j < 4; ++j) acc[i][j] = 0.0f;

    const u8* Ap = Qb8 + ((long long)z * SQ + (long long)y * 128) * DOUT;
    const u8* Bp = Kb8 + ((long long)z * SKV + (long long)x * 128) * DOUT;
    gemm_mainloop_fp8(acc, Ap, Bp, DOUT, DOUT, DOUT, smem, smem + 16384, wave, lane);

    const int wm = (wave & 1) * 64, wn = (wave >> 1) * 64;
    const int lm = lane & 15, quad = lane >> 4;
    u8* C = expS8 + (long long)z * SQ * SKV;
    const long long grow0 = (long long)z * SQ + (long long)y * 128;
#pragma unroll
    for (int i = 0; i < 4; ++i) {
        float rs[4] = {0.f, 0.f, 0.f, 0.f};
#pragma unroll
        for (int j = 0; j < 4; ++j) {
            const int row0 = y * 128 + wm + i * 16 + quad * 4;
            const int col = x * 128 + wn + j * 16 + lm;
#pragma unroll
            for (int r = 0; r < 4; ++r) {
                float e = __expf(acc[i][j][r] * SCORE_SCALE);
                rs[r] += e;
                C[(long long)(row0 + r) * SKV + swz_off(row0 + r, col)] = to_fp8(e * P_STORE_SCALE);
            }
        }
#pragma unroll
        for (int r = 0; r < 4; ++r) {
            float v = rs[r];
            v += __shfl_xor(v, 1, 64);
            v += __shfl_xor(v, 2, 64);
            v += __shfl_xor(v, 4, 64);
            v += __shfl_xor(v, 8, 64);
            if (lm == 0)
                atomicAdd(&l[grow0 + wm + i * 16 + quad * 4 + r], v);
        }
    }
}

// ---------------- out = (expS8 @ V8)*16/l + offset @ G ----------------
// grid 512: z=id%8, x=(id/8)%4, y=(id/8)/4
__global__ __launch_bounds__(256) void out_gemm(
    const u8* __restrict__ expS8, const u8* __restrict__ VT8,
    const bf16* __restrict__ offb, const bf16* __restrict__ Gb,
    const float* __restrict__ l, float* __restrict__ out)
{
    __shared__ __align__(16) u8 smem[32768];
    const int tid = threadIdx.x;
    const int wave = tid >> 6, lane = tid & 63;
    const int id = blockIdx.x;
    const int z = id & 7, x = (id >> 3) & 3, y = (id >> 3) >> 2;

    floatx4_t acc[4][4];
#pragma unroll
    for (int i = 0; i < 4; ++i)
#pragma unroll
        for (int j = 0; j < 4; ++j) acc[i][j] = 0.0f;

    // pass 1 (fp8): expS8 @ VT8^T, K = SKV
    {
        const u8* Ap = expS8 + (long long)z * SQ * SKV + (long long)y * 128 * SKV;
        const u8* Bp = VT8 + (long long)z * DOUT * SKV + (long long)x * 128 * SKV;
        gemm_mainloop_fp8(acc, Ap, Bp, SKV, SKV, SKV, smem, smem + 16384, wave, lane);
    }

    const int wm = (wave & 1) * 64, wn = (wave >> 1) * 64;
    const int lm = lane & 15, quad = lane >> 4;
    const long long grow0 = (long long)z * SQ + (long long)y * 128;

    // scale by 16/l (undo P_STORE_SCALE, normalize softmax)
#pragma unroll
    for (int i = 0; i < 4; ++i)
#pragma unroll
        for (int r = 0; r < 4; ++r) {
            const float inv = P_UNDO_SCALE / l[grow0 + wm + i * 16 + quad * 4 + r];
#pragma unroll
            for (int j = 0; j < 4; ++j) acc[i][j][r] *= inv;
        }

    // pass 2 (bf16): offset @ G, K = DIN
    {
        const bf16* Ap = offb + grow0 * DIN;
        const bf16* Bp = Gb + (long long)z * DOUT * DIN + (long long)x * 128 * DIN;
        gemm_mainloop(acc, Ap, Bp, DIN, DIN, DIN, (bf16*)smem, (bf16*)(smem + 16384), wave, lane);
    }

#pragma unroll
    for (int i = 0; i < 4; ++i)
#pragma unroll
        for (int j = 0; j < 4; ++j) {
            const long long row0 = grow0 + wm + i * 16 + quad * 4;
            const int col = x * 128 + wn + j * 16 + lm;
#pragma unroll
            for (int r = 0; r < 4; ++r)
                out[(row0 + r) * DOUT + col] = acc[i][j][r];
        }
}

extern "C" void kernel_launch(void* const* d_in, const int* in_sizes, int n_in,
                              void* d_out, int out_size, void* d_ws, size_t ws_size,
                              hipStream_t stream) {
    const float* query = (const float*)d_in[0];
    const float* key_ = (const float*)d_in[1];
    const float* value = (const float*)d_in[2];
    const float* offset = (const float*)d_in[3];
    const float* Wq = (const float*)d_in[4];
    const float* Wk = (const float*)d_in[5];
    const float* Wv = (const float*)d_in[6];
    const float* Woff = (const float*)d_in[7];
    float* out = (float*)d_out;

    char* ws = (char*)d_ws;
    const long long NE = (long long)NB * SQ * DIN;  // 8,388,608
    const long long MB = 1048576;

    u8* query8   = (u8*)(ws + 0 * MB);     // 8 MB, fp8 swz
    u8* key8     = (u8*)(ws + 8 * MB);     // 8 MB
    bf16* valueb = (bf16*)(ws + 16 * MB);  // 16 MB
    bf16* offsetb= (bf16*)(ws + 32 * MB);  // 16 MB
    u8* Qb8      = (u8*)(ws + 48 * MB);    // 8 MB
    u8* Kb8      = (u8*)(ws + 56 * MB);    // 8 MB
    bf16* VT     = (bf16*)(ws + 64 * MB);  // 16 MB
    u8* VT8      = (u8*)(ws + 80 * MB);    // 8 MB
    float* G32a  = (float*)(ws + 88 * MB); // 8 MB
    float* G32b  = (float*)(ws + 96 * MB); // 8 MB
    bf16* Gb     = (bf16*)(ws + 104 * MB); // 4 MB
    u8* WqT8     = (u8*)(ws + 108 * MB);            // 256 KB
    u8* WkT8     = (u8*)(ws + 108 * MB + 262144);   // 256 KB
    bf16* WvT    = (bf16*)(ws + 108 * MB + 524288); // 512 KB
    bf16* Woffb  = (bf16*)(ws + 109 * MB);          // 2 MB
    float* lbuf  = (float*)(ws + 111 * MB);         // 64 KB
    u8* expS8    = (u8*)(ws + 112 * MB);   // 32 MB
    // total 144 MB

    // 1. casts (query/key fp8+swz, value/offset/Woff bf16) + zero l
    CastArgs ca;
    ca.src[0] = query;  ca.dst[0] = query8;  ca.n4[0] = (int)(NE / 4); ca.mode[0] = 1;
    ca.src[1] = key_;   ca.dst[1] = key8;    ca.n4[1] = (int)(NE / 4); ca.mode[1] = 1;
    ca.src[2] = value;  ca.dst[2] = valueb;  ca.n4[2] = (int)(NE / 4); ca.mode[2] = 0;
    ca.src[3] = offset; ca.dst[3] = offsetb; ca.n4[3] = (int)(NE / 4); ca.mode[3] = 0;
    ca.src[4] = Woff;   ca.dst[4] = Woffb;   ca.n4[4] = (DIN * SKV) / 4; ca.mode[4] = 0;
    ca.src[5] = nullptr; ca.dst[5] = lbuf;   ca.n4[5] = (NB * SQ) / 4; ca.mode[5] = 2;
    cast_many<<<dim3(8192, 1, 6), 256, 0, stream>>>(ca);

    // 2. weight transposes: Wq,Wk -> fp8 swz x4; Wv -> bf16
    TWArgs tw;
    tw.src[0] = Wq; tw.src[1] = Wk; tw.src[2] = Wv;
    tw.dst[0] = WqT8; tw.dst[1] = WkT8; tw.dst[2] = WvT;
    transpose_w<<<dim3(16, 16, 3), dim3(32, 8), 0, stream>>>(tw);

    // 3. Q,K projections (fp8) + VT projection (bf16, also writes VT8)
    proj_gemm<<<dim3(1536), 256, 0, stream>>>(query8, key8, WqT8, WkT8, Qb8, Kb8,
                                              valueb, WvT, VT, VT8);

    // 4. G = (Woff @ V)^T, split-K2 into two fp32 buffers
    g_gemm<<<dim3(256), 256, 0, stream>>>(VT, Woffb, G32a, G32b);

    // 5. expS8 = exp(scores)/16 (fp8) + row sums l; tail blocks convert G32 -> Gb
    s_gemm_exp<<<dim3(2112), 256, 0, stream>>>(Qb8, Kb8, expS8, lbuf, G32a, G32b, Gb);

    // 6. out = (expS8 @ V8)*16/l + offset @ G
    out_gemm<<<dim3(512), 256, 0, stream>>>(expS8, VT8, offsetb, Gb, lbuf, out);
}

// Round 2
// 310.154 us; speedup vs baseline: 1.0741x; 1.0466x over previous
//
#include <hip/hip_runtime.h>
#include <hip/hip_bf16.h>
#include <stdint.h>

typedef __bf16 bf16;
typedef unsigned char u8;
typedef bf16 bf16x4_t __attribute__((ext_vector_type(4)));
typedef bf16 bf16x8_t __attribute__((ext_vector_type(8)));
typedef float floatx4_t __attribute__((ext_vector_type(4)));

#define NB 8
#define SQ 2048
#define SKV 2048
#define DIN 512
#define DOUT 512

// scores = (q*4)(k*4)/16/sqrt(512): 1/(16*sqrt(512))
#define SCORE_SCALE 0.0027621358640099513f
// expS stored as e/16 to stay under fp8 e4m3 max (448)
#define P_STORE_SCALE 0.0625f
#define P_UNDO_SCALE 16.0f

__device__ __forceinline__ void load_lds16(const void* g, void* l) {
    __builtin_amdgcn_global_load_lds(
        (const __attribute__((address_space(1))) unsigned int*)g,
        (__attribute__((address_space(3))) unsigned int*)l, 16, 0, 0);
}

__device__ __forceinline__ u8 to_fp8(float f) {
    int v = __builtin_amdgcn_cvt_pk_fp8_f32(f, 0.f, 0, false);
    return (u8)(v & 0xff);
}
__device__ __forceinline__ unsigned int pack_fp8x4(float a, float b, float c, float d) {
    int lo = __builtin_amdgcn_cvt_pk_fp8_f32(a, b, 0, false);
    int all = __builtin_amdgcn_cvt_pk_fp8_f32(c, d, lo, true);
    return (unsigned int)all;
}

// 16-B-granule XOR swizzle within each 64-B k-block, key = (row>>1)&3.
// LDS row stride is 64 B = 16 banks, so bank group = {row&1, granule}. Keying
// the XOR off (row>>1)&3 (NOT row&3, whose bit0 duplicates the row&1 bank bit)
// spreads the 8 same-granule rows of a quad across all 8 bank groups -> 2-way
// (free). Producers write with it; LDS readers undo it. Applied to BOTH fp8
// and bf16 operand buffers (all are consumed only through the mainloops).
__device__ __forceinline__ int swz_off(int row, int col) {
    return (col & ~63) | ((((col >> 4) & 3) ^ ((row >> 1) & 3)) << 4) | (col & 15);
}

// ---------------- cast: query/key -> fp8(swz), value/offset/Woff -> bf16(swz), zero l ----------------
struct CastArgs {
    const float* src[6];
    void* dst[6];
    int n4[6];
    int mode[6];     // 0=bf16 swizzled, 1=fp8 swizzled (row len 512), 2=zero-f32
    int rowshift[6]; // log2(row bytes) for mode 0
};
__global__ void cast_many(CastArgs a) {
    int z = blockIdx.z;
    int i = blockIdx.x * blockDim.x + threadIdx.x;
    if (i >= a.n4[z]) return;
    if (a.mode[z] == 2) {
        ((float4*)a.dst[z])[i] = make_float4(0.f, 0.f, 0.f, 0.f);
        return;
    }
    float4 f = ((const float4*)a.src[z])[i];
    if (a.mode[z] == 1) {
        int row = i >> 7;            // 128 float4-groups per 512-elem row
        int k0 = (i & 127) * 4;      // 4 bytes, within one 16-B granule
        u8* d = (u8*)a.dst[z];
        *(unsigned int*)&d[row * 512 + swz_off(row, k0)] = pack_fp8x4(f.x, f.y, f.z, f.w);
    } else {
        const int rs = a.rowshift[z];
        const long long g8 = (long long)i * 8;       // byte offset of this 8-B chunk
        const int row = (int)(g8 >> rs);
        const int cb = (int)(g8 - ((long long)row << rs));
        bf16x4_t o = { (bf16)f.x, (bf16)f.y, (bf16)f.z, (bf16)f.w };
        u8* d = (u8*)a.dst[z];
        *(bf16x4_t*)&d[((long long)row << rs) + swz_off(row, cb)] = o;
    }
}

// ---------------- weight transpose f32[512,512] -> fp8(swz, x4) for Wq/Wk, bf16(swz) for Wv ----------------
struct TWArgs { const float* src[3]; void* dst[3]; };
__global__ void transpose_w(TWArgs a) {
    __shared__ float t[32][33];
    const float* src = a.src[blockIdx.z];
    int tx = threadIdx.x, ty = threadIdx.y;
    int x0 = blockIdx.x * 32, y0 = blockIdx.y * 32;
#pragma unroll
    for (int j = 0; j < 4; ++j)
        t[ty + 8 * j][tx] = src[(y0 + ty + 8 * j) * DIN + x0 + tx];
    __syncthreads();
    if (blockIdx.z <= 1) {
        u8* d8 = (u8*)a.dst[blockIdx.z];
#pragma unroll
        for (int j = 0; j < 4; ++j) {
            int row = x0 + ty + 8 * j, col = y0 + tx;
            d8[row * 512 + swz_off(row, col)] = to_fp8(t[tx][ty + 8 * j] * 4.0f);
        }
    } else {
        u8* db = (u8*)a.dst[2];
#pragma unroll
        for (int j = 0; j < 4; ++j) {
            int row = x0 + ty + 8 * j, cb = (y0 + tx) * 2;
            *(bf16*)&db[(long long)row * 1024 + swz_off(row, cb)] = (bf16)t[tx][ty + 8 * j];
        }
    }
}

// ---------------- bf16 NT mainloop, BK=32, double-buffered + pipelined ----------------
// Operand rows are 64-B-blocked with 16-B granule XOR((row>>1)&3) swizzle in
// global memory; staging copies them linearly, the fragment read undoes it.
__device__ __forceinline__ void gemm_mainloop(
    floatx4_t (&acc)[4][4], const bf16* __restrict__ Ap, const bf16* __restrict__ Bp,
    int lda, int ldb, int K, bf16* As, bf16* Bs, int wave, int lane)
{
    const int wm = (wave & 1) * 64, wn = (wave >> 1) * 64;
    const int lm = lane & 15, quad = lane >> 4;
    const int srow = lane >> 2, scol = (lane & 3) * 8;
    const int key = (lm >> 1) & 3;

    auto STAGE = [&](int buf, int k0) {
#pragma unroll
        for (int t = 0; t < 2; ++t) {
            const int r0 = (wave * 2 + t) * 16;
            load_lds16(Ap + (long long)(r0 + srow) * lda + (k0 + scol),
                       &As[buf * 4096 + r0 * 32]);
            load_lds16(Bp + (long long)(r0 + srow) * ldb + (k0 + scol),
                       &Bs[buf * 4096 + r0 * 32]);
        }
    };

    STAGE(0, 0);
    __syncthreads();
    int cur = 0;
    for (int k0 = 0; k0 < K; k0 += 32) {
        if (k0 + 32 < K) STAGE(cur ^ 1, k0 + 32);
        bf16x8_t af[4], bfr[4];
#pragma unroll
        for (int i = 0; i < 4; ++i)
            af[i] = *(const bf16x8_t*)&As[cur * 4096 + (wm + i * 16 + lm) * 32 + (quad ^ key) * 8];
#pragma unroll
        for (int i = 0; i < 4; ++i)
            bfr[i] = *(const bf16x8_t*)&Bs[cur * 4096 + (wn + i * 16 + lm) * 32 + (quad ^ key) * 8];
#pragma unroll
        for (int i = 0; i < 4; ++i)
#pragma unroll
            for (int j = 0; j < 4; ++j)
                acc[i][j] = __builtin_amdgcn_mfma_f32_16x16x32_bf16(af[i], bfr[j], acc[i][j], 0, 0, 0);
        __syncthreads();
        cur ^= 1;
    }
}

// ---------------- fp8 NT mainloop, BK=64, double-buffered + pipelined ----------------
// A/B rows are 64-B-blocked with 16-B granule XOR((row>>1)&3) swizzle.
__device__ __forceinline__ void gemm_mainloop_fp8(
    floatx4_t (&acc)[4][4], const u8* __restrict__ Ap, const u8* __restrict__ Bp,
    int lda, int ldb, int K, u8* As, u8* Bs, int wave, int lane)
{
    const int wm = (wave & 1) * 64, wn = (wave >> 1) * 64;
    const int lm = lane & 15, quad = lane >> 4;
    const int srow = lane >> 2, scol = (lane & 3) * 16;  // 16 rows x 64 B per inst
    const int key = (lm >> 1) & 3;
    const int inner = (quad & 1) * 8;
    const int gh = quad >> 1;

    auto STAGE = [&](int buf, int k0) {
#pragma unroll
        for (int t = 0; t < 2; ++t) {
            const int r0 = (wave * 2 + t) * 16;
            load_lds16(Ap + (long long)(r0 + srow) * lda + k0 + scol, &As[buf * 8192 + r0 * 64]);
            load_lds16(Bp + (long long)(r0 + srow) * ldb + k0 + scol, &Bs[buf * 8192 + r0 * 64]);
        }
    };

    STAGE(0, 0);
    __syncthreads();
    int cur = 0;
    for (int k0 = 0; k0 < K; k0 += 64) {
        if (k0 + 64 < K) STAGE(cur ^ 1, k0 + 64);
#pragma unroll
        for (int p = 0; p < 2; ++p) {
            const int gL = p * 2 + gh;
            const int koff = ((gL ^ key) << 4) + inner;  // undo producer swizzle
            long long a[4], b[4];
#pragma unroll
            for (int i = 0; i < 4; ++i)
                a[i] = *(const long long*)&As[cur * 8192 + (wm + i * 16 + lm) * 64 + koff];
#pragma unroll
            for (int i = 0; i < 4; ++i)
                b[i] = *(const long long*)&Bs[cur * 8192 + (wn + i * 16 + lm) * 64 + koff];
#pragma unroll
            for (int i = 0; i < 4; ++i)
#pragma unroll
                for (int j = 0; j < 4; ++j)
                    acc[i][j] = __builtin_amdgcn_mfma_f32_16x16x32_fp8_fp8(a[i], b[j], acc[i][j], 0, 0, 0);
        }
        __syncthreads();
        cur ^= 1;
    }
}

// ---------------- phase 1: Q/K projections (fp8) + VT projection (bf16) ----------------
// ids [0,1024): fp8 Q/K proj. xcd=id%8, t=id/8, m=t%4, gg=xcd+8*(t/4): y=gg%128, z=gg/128
// ids [1024,1536): VT[d,kv] = sum_k WvT[d,k]*value[kv,k]; z=id2%8, ym=(id2/8)%4, xn=(id2/8)/4
__global__ __launch_bounds__(256) void proj_gemm(
    const u8* __restrict__ query8, const u8* __restrict__ key8,
    const u8* __restrict__ WqT8, const u8* __restrict__ WkT8,
    u8* __restrict__ Qb8, u8* __restrict__ Kb8,
    const bf16* __restrict__ valueb, const bf16* __restrict__ WvT,
    bf16* __restrict__ VT, u8* __restrict__ VT8)
{
    __shared__ __align__(16) u8 smem[32768];
    const int tid = threadIdx.x;
    const int wave = tid >> 6, lane = tid & 63;
    const int wm = (wave & 1) * 64, wn = (wave >> 1) * 64;
    const int lm = lane & 15, quad = lane >> 4;
    const int id = blockIdx.x;

    floatx4_t acc[4][4];
#pragma unroll
    for (int i = 0; i < 4; ++i)
#pragma unroll
        for (int j = 0; j < 4; ++j) acc[i][j] = 0.0f;

    if (id < 1024) {
        const int xcd = id & 7, t = id >> 3, m = t & 3;
        const int gg = xcd + 8 * (t >> 2);
        const int y = gg & 127, z = gg >> 7;
        const u8* Ap = (z ? key8 : query8) + (long long)y * 128 * DIN;
        const u8* Bp = (z ? WkT8 : WqT8) + (long long)m * 128 * DIN;
        gemm_mainloop_fp8(acc, Ap, Bp, DIN, DIN, DIN, smem, smem + 16384, wave, lane);
        u8* C = z ? Kb8 : Qb8;
#pragma unroll
        for (int i = 0; i < 4; ++i)
#pragma unroll
            for (int j = 0; j < 4; ++j) {
                const int row0 = y * 128 + wm + i * 16 + quad * 4;
                const int col = m * 128 + wn + j * 16 + lm;
#pragma unroll
                for (int r = 0; r < 4; ++r)
                    C[(long long)(row0 + r) * DOUT + swz_off(row0 + r, col)] = to_fp8(acc[i][j][r]);
            }
    } else {
        const int id2 = id - 1024;
        const int z = id2 & 7, r2 = id2 >> 3;
        const int ym = r2 & 3, xn = r2 >> 2;
        const bf16* Ap = WvT + (long long)ym * 128 * DIN;
        const bf16* Bp = valueb + (long long)z * (SKV * DIN) + (long long)xn * 128 * DIN;
        gemm_mainloop(acc, Ap, Bp, DIN, DIN, DIN, (bf16*)smem, (bf16*)(smem + 16384), wave, lane);
        u8* C = (u8*)(VT + (long long)z * (DOUT * SKV));
        u8* C8 = VT8 + (long long)z * (DOUT * SKV);
#pragma unroll
        for (int i = 0; i < 4; ++i)
#pragma unroll
            for (int j = 0; j < 4; ++j) {
                const int row0 = ym * 128 + wm + i * 16 + quad * 4;
                const int col = xn * 128 + wn + j * 16 + lm;
#pragma unroll
                for (int r = 0; r < 4; ++r) {
                    float v = acc[i][j][r];
                    const int rr = row0 + r;
                    *(bf16*)&C[(long long)rr * (SKV * 2) + swz_off(rr, col * 2)] = (bf16)v;
                    C8[(long long)rr * SKV + swz_off(rr, col)] = to_fp8(v);
                }
            }
    }
}

// ---------------- G split-K2: G32h = (Woff @ V)^T partial, bf16 path ----------------
// grid 256: z=id%8, h=(id>>3)&1, x=(id>>4)&3, y=(id>>6)&3
__global__ __launch_bounds__(256) void g_gemm(
    const bf16* __restrict__ VT, const bf16* __restrict__ Woffb,
    float* __restrict__ G32a, float* __restrict__ G32b)
{
    __shared__ __align__(16) u8 smem[32768];
    const int tid = threadIdx.x;
    const int wave = tid >> 6, lane = tid & 63;
    const int id = blockIdx.x;
    const int z = id & 7, h = (id >> 3) & 1, x = (id >> 4) & 3, y = (id >> 6) & 3;

    floatx4_t acc[4][4];
#pragma unroll
    for (int i = 0; i < 4; ++i)
#pragma unroll
        for (int j = 0; j < 4; ++j) acc[i][j] = 0.0f;

    const bf16* Ap = VT + (long long)z * (DOUT * SKV) + (long long)y * 128 * SKV + h * 1024;
    const bf16* Bp = Woffb + (long long)x * 128 * SKV + h * 1024;
    gemm_mainloop(acc, Ap, Bp, SKV, SKV, 1024, (bf16*)smem, (bf16*)(smem + 16384), wave, lane);

    const int wm = (wave & 1) * 64, wn = (wave >> 1) * 64;
    const int lm = lane & 15, quad = lane >> 4;
    float* C = (h ? G32b : G32a) + (long long)z * (DOUT * DIN);
#pragma unroll
    for (int i = 0; i < 4; ++i)
#pragma unroll
        for (int j = 0; j < 4; ++j) {
            const int row0 = y * 128 + wm + i * 16 + quad * 4;
            const int col = x * 128 + wn + j * 16 + lm;
#pragma unroll
            for (int r = 0; r < 4; ++r)
                C[(long long)(row0 + r) * DIN + col] = acc[i][j][r];
        }
}

// ---------------- S-GEMM fp8 + exp epilogue + row sums; ids>=2048 convert G32->Gb ----------------
// grid 2112: s-blocks: z=id%8, x=(id/8)%16, y=(id/8)/16
__global__ __launch_bounds__(256) void s_gemm_exp(
    const u8* __restrict__ Qb8, const u8* __restrict__ Kb8,
    u8* __restrict__ expS8, float* __restrict__ l,
    const float* __restrict__ G32a, const float* __restrict__ G32b,
    bf16* __restrict__ Gb)
{
    __shared__ __align__(16) u8 smem[32768];
    const int tid = threadIdx.x;
    const int id = blockIdx.x;
    if (id >= 2048) {
        // convert G32a+G32b -> Gb (swizzled, rows = 512 bf16 = 1024 B)
        const int base = (id - 2048) * 256 + tid;
        const float4* A4 = (const float4*)G32a;
        const float4* B4 = (const float4*)G32b;
        u8* O = (u8*)Gb;
#pragma unroll 4
        for (int t = 0; t < 32; ++t) {
            const int idx = base + t * 16384;
            float4 a = A4[idx], b = B4[idx];
            bf16x4_t o = { (bf16)(a.x + b.x), (bf16)(a.y + b.y),
                           (bf16)(a.z + b.z), (bf16)(a.w + b.w) };
            const long long boff = (long long)idx * 8;
            const int row = (int)(boff >> 10);
            const int cb = (int)(boff & 1023);
            *(bf16x4_t*)&O[((long long)row << 10) + swz_off(row, cb)] = o;
        }
        return;
    }
    const int wave = tid >> 6, lane = tid & 63;
    const int z = id & 7, x = (id >> 3) & 15, y = (id >> 3) >> 4;

    floatx4_t acc[4][4];
#pragma unroll
    for (int i = 0; i < 4; ++i)
#pragma unroll
        for (int j = 0; j < 4; ++j) acc[i][j] = 0.0f;

    const u8* Ap = Qb8 + ((long long)z * SQ + (long long)y * 128) * DOUT;
    const u8* Bp = Kb8 + ((long long)z * SKV + (long long)x * 128) * DOUT;
    gemm_mainloop_fp8(acc, Ap, Bp, DOUT, DOUT, DOUT, smem, smem + 16384, wave, lane);

    const int wm = (wave & 1) * 64, wn = (wave >> 1) * 64;
    const int lm = lane & 15, quad = lane >> 4;
    u8* C = expS8 + (long long)z * SQ * SKV;
    const long long grow0 = (long long)z * SQ + (long long)y * 128;
#pragma unroll
    for (int i = 0; i < 4; ++i) {
        float rs[4] = {0.f, 0.f, 0.f, 0.f};
#pragma unroll
        for (int j = 0; j < 4; ++j) {
            const int row0 = y * 128 + wm + i * 16 + quad * 4;
            const int col = x * 128 + wn + j * 16 + lm;
#pragma unroll
            for (int r = 0; r < 4; ++r) {
                float e = __expf(acc[i][j][r] * SCORE_SCALE);
                rs[r] += e;
                C[(long long)(row0 + r) * SKV + swz_off(row0 + r, col)] = to_fp8(e * P_STORE_SCALE);
            }
        }
#pragma unroll
        for (int r = 0; r < 4; ++r) {
            float v = rs[r];
            v += __shfl_xor(v, 1, 64);
            v += __shfl_xor(v, 2, 64);
            v += __shfl_xor(v, 4, 64);
            v += __shfl_xor(v, 8, 64);
            if (lm == 0)
                atomicAdd(&l[grow0 + wm + i * 16 + quad * 4 + r], v);
        }
    }
}

// ---------------- out = (expS8 @ V8)*16/l + offset @ G ----------------
// grid 512: z=id%8, x=(id/8)%4, y=(id/8)/4
__global__ __launch_bounds__(256) void out_gemm(
    const u8* __restrict__ expS8, const u8* __restrict__ VT8,
    const bf16* __restrict__ offb, const bf16* __restrict__ Gb,
    const float* __restrict__ l, float* __restrict__ out)
{
    __shared__ __align__(16) u8 smem[32768];
    const int tid = threadIdx.x;
    const int wave = tid >> 6, lane = tid & 63;
    const int id = blockIdx.x;
    const int z = id & 7, x = (id >> 3) & 3, y = (id >> 3) >> 2;

    floatx4_t acc[4][4];
#pragma unroll
    for (int i = 0; i < 4; ++i)
#pragma unroll
        for (int j = 0; j < 4; ++j) acc[i][j] = 0.0f;

    // pass 1 (fp8): expS8 @ VT8^T, K = SKV
    {
        const u8* Ap = expS8 + (long long)z * SQ * SKV + (long long)y * 128 * SKV;
        const u8* Bp = VT8 + (long long)z * DOUT * SKV + (long long)x * 128 * SKV;
        gemm_mainloop_fp8(acc, Ap, Bp, SKV, SKV, SKV, smem, smem + 16384, wave, lane);
    }

    const int wm = (wave & 1) * 64, wn = (wave >> 1) * 64;
    const int lm = lane & 15, quad = lane >> 4;
    const long long grow0 = (long long)z * SQ + (long long)y * 128;

    // scale by 16/l (undo P_STORE_SCALE, normalize softmax)
#pragma unroll
    for (int i = 0; i < 4; ++i)
#pragma unroll
        for (int r = 0; r < 4; ++r) {
            const float inv = P_UNDO_SCALE / l[grow0 + wm + i * 16 + quad * 4 + r];
#pragma unroll
            for (int j = 0; j < 4; ++j) acc[i][j][r] *= inv;
        }

    // pass 2 (bf16): offset @ G, K = DIN
    {
        const bf16* Ap = offb + grow0 * DIN;
        const bf16* Bp = Gb + (long long)z * DOUT * DIN + (long long)x * 128 * DIN;
        gemm_mainloop(acc, Ap, Bp, DIN, DIN, DIN, (bf16*)smem, (bf16*)(smem + 16384), wave, lane);
    }

#pragma unroll
    for (int i = 0; i < 4; ++i)
#pragma unroll
        for (int j = 0; j < 4; ++j) {
            const long long row0 = grow0 + wm + i * 16 + quad * 4;
            const int col = x * 128 + wn + j * 16 + lm;
#pragma unroll
            for (int r = 0; r < 4; ++r)
                out[(row0 + r) * DOUT + col] = acc[i][j][r];
        }
}

extern "C" void kernel_launch(void* const* d_in, const int* in_sizes, int n_in,
                              void* d_out, int out_size, void* d_ws, size_t ws_size,
                              hipStream_t stream) {
    const float* query = (const float*)d_in[0];
    const float* key_ = (const float*)d_in[1];
    const float* value = (const float*)d_in[2];
    const float* offset = (const float*)d_in[3];
    const float* Wq = (const float*)d_in[4];
    const float* Wk = (const float*)d_in[5];
    const float* Wv = (const float*)d_in[6];
    const float* Woff = (const float*)d_in[7];
    float* out = (float*)d_out;

    char* ws = (char*)d_ws;
    const long long NE = (long long)NB * SQ * DIN;  // 8,388,608
    const long long MB = 1048576;

    u8* query8   = (u8*)(ws + 0 * MB);     // 8 MB, fp8 swz
    u8* key8     = (u8*)(ws + 8 * MB);     // 8 MB
    bf16* valueb = (bf16*)(ws + 16 * MB);  // 16 MB, bf16 swz
    bf16* offsetb= (bf16*)(ws + 32 * MB);  // 16 MB, bf16 swz
    u8* Qb8      = (u8*)(ws + 48 * MB);    // 8 MB
    u8* Kb8      = (u8*)(ws + 56 * MB);    // 8 MB
    bf16* VT     = (bf16*)(ws + 64 * MB);  // 16 MB, bf16 swz
    u8* VT8      = (u8*)(ws + 80 * MB);    // 8 MB
    float* G32a  = (float*)(ws + 88 * MB); // 8 MB
    float* G32b  = (float*)(ws + 96 * MB); // 8 MB
    bf16* Gb     = (bf16*)(ws + 104 * MB); // 4 MB, bf16 swz
    u8* WqT8     = (u8*)(ws + 108 * MB);            // 256 KB
    u8* WkT8     = (u8*)(ws + 108 * MB + 262144);   // 256 KB
    bf16* WvT    = (bf16*)(ws + 108 * MB + 524288); // 512 KB, bf16 swz
    bf16* Woffb  = (bf16*)(ws + 109 * MB);          // 2 MB, bf16 swz
    float* lbuf  = (float*)(ws + 111 * MB);         // 64 KB
    u8* expS8    = (u8*)(ws + 112 * MB);   // 32 MB
    // total 144 MB

    // 1. casts (query/key fp8+swz, value/offset/Woff bf16+swz) + zero l
    CastArgs ca;
    ca.src[0] = query;  ca.dst[0] = query8;  ca.n4[0] = (int)(NE / 4); ca.mode[0] = 1; ca.rowshift[0] = 0;
    ca.src[1] = key_;   ca.dst[1] = key8;    ca.n4[1] = (int)(NE / 4); ca.mode[1] = 1; ca.rowshift[1] = 0;
    ca.src[2] = value;  ca.dst[2] = valueb;  ca.n4[2] = (int)(NE / 4); ca.mode[2] = 0; ca.rowshift[2] = 10;
    ca.src[3] = offset; ca.dst[3] = offsetb; ca.n4[3] = (int)(NE / 4); ca.mode[3] = 0; ca.rowshift[3] = 10;
    ca.src[4] = Woff;   ca.dst[4] = Woffb;   ca.n4[4] = (DIN * SKV) / 4; ca.mode[4] = 0; ca.rowshift[4] = 12;
    ca.src[5] = nullptr; ca.dst[5] = lbuf;   ca.n4[5] = (NB * SQ) / 4; ca.mode[5] = 2; ca.rowshift[5] = 0;
    cast_many<<<dim3(8192, 1, 6), 256, 0, stream>>>(ca);

    // 2. weight transposes: Wq,Wk -> fp8 swz x4; Wv -> bf16 swz
    TWArgs tw;
    tw.src[0] = Wq; tw.src[1] = Wk; tw.src[2] = Wv;
    tw.dst[0] = WqT8; tw.dst[1] = WkT8; tw.dst[2] = WvT;
    transpose_w<<<dim3(16, 16, 3), dim3(32, 8), 0, stream>>>(tw);

    // 3. Q,K projections (fp8) + VT projection (bf16, also writes VT8)
    proj_gemm<<<dim3(1536), 256, 0, stream>>>(query8, key8, WqT8, WkT8, Qb8, Kb8,
                                              valueb, WvT, VT, VT8);

    // 4. G = (Woff @ V)^T, split-K2 into two fp32 buffers
    g_gemm<<<dim3(256), 256, 0, stream>>>(VT, Woffb, G32a, G32b);

    // 5. expS8 = exp(scores)/16 (fp8) + row sums l; tail blocks convert G32 -> Gb
    s_gemm_exp<<<dim3(2112), 256, 0, stream>>>(Qb8, Kb8, expS8, lbuf, G32a, G32b, Gb);

    // 6. out = (expS8 @ V8)*16/l + offset @ G
    out_gemm<<<dim3(512), 256, 0, stream>>>(expS8, VT8, offsetb, Gb, lbuf, out);
}

// Round 4
// 304.126 us; speedup vs baseline: 1.0954x; 1.0198x over previous
//
#include <hip/hip_runtime.h>
#include <hip/hip_bf16.h>
#include <stdint.h>

typedef __bf16 bf16;
typedef unsigned char u8;
typedef bf16 bf16x4_t __attribute__((ext_vector_type(4)));
typedef bf16 bf16x8_t __attribute__((ext_vector_type(8)));
typedef float floatx4_t __attribute__((ext_vector_type(4)));

#define NB 8
#define SQ 2048
#define SKV 2048
#define DIN 512
#define DOUT 512

// scores = (q*4)(k*4)/16/sqrt(512): 1/(16*sqrt(512))
#define SCORE_SCALE 0.0027621358640099513f
// expS stored as e/16 to stay under fp8 e4m3 max (448)
#define P_STORE_SCALE 0.0625f
#define P_UNDO_SCALE 16.0f

__device__ __forceinline__ void load_lds16(const void* g, void* l) {
    __builtin_amdgcn_global_load_lds(
        (const __attribute__((address_space(1))) unsigned int*)g,
        (__attribute__((address_space(3))) unsigned int*)l, 16, 0, 0);
}

__device__ __forceinline__ u8 to_fp8(float f) {
    int v = __builtin_amdgcn_cvt_pk_fp8_f32(f, 0.f, 0, false);
    return (u8)(v & 0xff);
}
__device__ __forceinline__ unsigned int pack_fp8x4(float a, float b, float c, float d) {
    int lo = __builtin_amdgcn_cvt_pk_fp8_f32(a, b, 0, false);
    int all = __builtin_amdgcn_cvt_pk_fp8_f32(c, d, lo, true);
    return (unsigned int)all;
}

// 16-B-granule XOR swizzle within each 64-B k-block, key = (row>>1)&3.
// LDS row stride is 64 B = 16 banks, so bank group = {row&1, granule}. Keying
// the XOR off (row>>1)&3 (NOT row&3, whose bit0 duplicates the row&1 bank bit)
// spreads the 8 same-granule rows of a quad across all 8 bank groups -> 2-way
// (free). Producers write with it; LDS readers undo it. Applied to BOTH fp8
// and bf16 operand buffers (all are consumed only through the mainloops).
__device__ __forceinline__ int swz_off(int row, int col) {
    return (col & ~63) | ((((col >> 4) & 3) ^ ((row >> 1) & 3)) << 4) | (col & 15);
}

// ---------------- cast: query/key -> fp8(swz), value/offset/Woff -> bf16(swz), zero l ----------------
// 4 independent float4s per thread (64 B) for memory-level parallelism; one
// float4/thread was latency-bound at 2.1 TB/s. All slice sizes divide 1024 so
// blocks are fully-active or fully-idle (no tails).
struct CastArgs {
    const float* src[6];
    void* dst[6];
    int n4[6];
    int mode[6];     // 0=bf16 swizzled, 1=fp8 swizzled (row len 512), 2=zero-f32
    int rowshift[6]; // log2(row bytes) for mode 0
};
__global__ __launch_bounds__(256) void cast_many(CastArgs a) {
    const int z = blockIdx.z;
    const int n4 = a.n4[z];
    const int base = blockIdx.x * 1024 + threadIdx.x;
    if (base >= n4) return;
    if (a.mode[z] == 2) {
#pragma unroll
        for (int k = 0; k < 4; ++k)
            ((float4*)a.dst[z])[base + k * 256] = make_float4(0.f, 0.f, 0.f, 0.f);
        return;
    }
    const float4* s4 = (const float4*)a.src[z];
    float4 f[4];
#pragma unroll
    for (int k = 0; k < 4; ++k) f[k] = s4[base + k * 256];
    if (a.mode[z] == 1) {
        u8* d = (u8*)a.dst[z];
#pragma unroll
        for (int k = 0; k < 4; ++k) {
            const int i = base + k * 256;
            const int row = i >> 7;          // 128 float4-groups per 512-elem row
            const int k0 = (i & 127) * 4;    // 4 bytes, within one 16-B granule
            *(unsigned int*)&d[row * 512 + swz_off(row, k0)] =
                pack_fp8x4(f[k].x, f[k].y, f[k].z, f[k].w);
        }
    } else {
        const int rs = a.rowshift[z];
        u8* d = (u8*)a.dst[z];
#pragma unroll
        for (int k = 0; k < 4; ++k) {
            const int i = base + k * 256;
            const long long g8 = (long long)i * 8;   // byte offset of this 8-B chunk
            const int row = (int)(g8 >> rs);
            const int cb = (int)(g8 - ((long long)row << rs));
            bf16x4_t o = { (bf16)f[k].x, (bf16)f[k].y, (bf16)f[k].z, (bf16)f[k].w };
            *(bf16x4_t*)&d[((long long)row << rs) + swz_off(row, cb)] = o;
        }
    }
}

// ---------------- weight transpose f32[512,512] -> fp8(swz, x4) for Wq/Wk, bf16(swz) for Wv ----------------
struct TWArgs { const float* src[3]; void* dst[3]; };
__global__ void transpose_w(TWArgs a) {
    __shared__ float t[32][33];
    const float* src = a.src[blockIdx.z];
    int tx = threadIdx.x, ty = threadIdx.y;
    int x0 = blockIdx.x * 32, y0 = blockIdx.y * 32;
#pragma unroll
    for (int j = 0; j < 4; ++j)
        t[ty + 8 * j][tx] = src[(y0 + ty + 8 * j) * DIN + x0 + tx];
    __syncthreads();
    if (blockIdx.z <= 1) {
        u8* d8 = (u8*)a.dst[blockIdx.z];
#pragma unroll
        for (int j = 0; j < 4; ++j) {
            int row = x0 + ty + 8 * j, col = y0 + tx;
            d8[row * 512 + swz_off(row, col)] = to_fp8(t[tx][ty + 8 * j] * 4.0f);
        }
    } else {
        u8* db = (u8*)a.dst[2];
#pragma unroll
        for (int j = 0; j < 4; ++j) {
            int row = x0 + ty + 8 * j, cb = (y0 + tx) * 2;
            *(bf16*)&db[(long long)row * 1024 + swz_off(row, cb)] = (bf16)t[tx][ty + 8 * j];
        }
    }
}

// ---------------- bf16 NT mainloop, BK=32, double-buffered + pipelined ----------------
// Operand rows are 64-B-blocked with 16-B granule XOR((row>>1)&3) swizzle in
// global memory; staging copies them linearly, the fragment read undoes it.
__device__ __forceinline__ void gemm_mainloop(
    floatx4_t (&acc)[4][4], const bf16* __restrict__ Ap, const bf16* __restrict__ Bp,
    int lda, int ldb, int K, bf16* As, bf16* Bs, int wave, int lane)
{
    const int wm = (wave & 1) * 64, wn = (wave >> 1) * 64;
    const int lm = lane & 15, quad = lane >> 4;
    const int srow = lane >> 2, scol = (lane & 3) * 8;
    const int key = (lm >> 1) & 3;

    auto STAGE = [&](int buf, int k0) {
#pragma unroll
        for (int t = 0; t < 2; ++t) {
            const int r0 = (wave * 2 + t) * 16;
            load_lds16(Ap + (long long)(r0 + srow) * lda + (k0 + scol),
                       &As[buf * 4096 + r0 * 32]);
            load_lds16(Bp + (long long)(r0 + srow) * ldb + (k0 + scol),
                       &Bs[buf * 4096 + r0 * 32]);
        }
    };

    STAGE(0, 0);
    __syncthreads();
    int cur = 0;
    for (int k0 = 0; k0 < K; k0 += 32) {
        if (k0 + 32 < K) STAGE(cur ^ 1, k0 + 32);
        bf16x8_t af[4], bfr[4];
#pragma unroll
        for (int i = 0; i < 4; ++i)
            af[i] = *(const bf16x8_t*)&As[cur * 4096 + (wm + i * 16 + lm) * 32 + (quad ^ key) * 8];
#pragma unroll
        for (int i = 0; i < 4; ++i)
            bfr[i] = *(const bf16x8_t*)&Bs[cur * 4096 + (wn + i * 16 + lm) * 32 + (quad ^ key) * 8];
#pragma unroll
        for (int i = 0; i < 4; ++i)
#pragma unroll
            for (int j = 0; j < 4; ++j)
                acc[i][j] = __builtin_amdgcn_mfma_f32_16x16x32_bf16(af[i], bfr[j], acc[i][j], 0, 0, 0);
        __syncthreads();
        cur ^= 1;
    }
}

// ---------------- fp8 NT mainloop, BK=64, double-buffered + pipelined ----------------
// A/B rows are 64-B-blocked with 16-B granule XOR((row>>1)&3) swizzle.
__device__ __forceinline__ void gemm_mainloop_fp8(
    floatx4_t (&acc)[4][4], const u8* __restrict__ Ap, const u8* __restrict__ Bp,
    int lda, int ldb, int K, u8* As, u8* Bs, int wave, int lane)
{
    const int wm = (wave & 1) * 64, wn = (wave >> 1) * 64;
    const int lm = lane & 15, quad = lane >> 4;
    const int srow = lane >> 2, scol = (lane & 3) * 16;  // 16 rows x 64 B per inst
    const int key = (lm >> 1) & 3;
    const int inner = (quad & 1) * 8;
    const int gh = quad >> 1;

    auto STAGE = [&](int buf, int k0) {
#pragma unroll
        for (int t = 0; t < 2; ++t) {
            const int r0 = (wave * 2 + t) * 16;
            load_lds16(Ap + (long long)(r0 + srow) * lda + k0 + scol, &As[buf * 8192 + r0 * 64]);
            load_lds16(Bp + (long long)(r0 + srow) * ldb + k0 + scol, &Bs[buf * 8192 + r0 * 64]);
        }
    };

    STAGE(0, 0);
    __syncthreads();
    int cur = 0;
    for (int k0 = 0; k0 < K; k0 += 64) {
        if (k0 + 64 < K) STAGE(cur ^ 1, k0 + 64);
#pragma unroll
        for (int p = 0; p < 2; ++p) {
            const int gL = p * 2 + gh;
            const int koff = ((gL ^ key) << 4) + inner;  // undo producer swizzle
            long long a[4], b[4];
#pragma unroll
            for (int i = 0; i < 4; ++i)
                a[i] = *(const long long*)&As[cur * 8192 + (wm + i * 16 + lm) * 64 + koff];
#pragma unroll
            for (int i = 0; i < 4; ++i)
                b[i] = *(const long long*)&Bs[cur * 8192 + (wn + i * 16 + lm) * 64 + koff];
#pragma unroll
            for (int i = 0; i < 4; ++i)
#pragma unroll
                for (int j = 0; j < 4; ++j)
                    acc[i][j] = __builtin_amdgcn_mfma_f32_16x16x32_fp8_fp8(a[i], b[j], acc[i][j], 0, 0, 0);
        }
        __syncthreads();
        cur ^= 1;
    }
}

// ---------------- phase 1: Q/K projections (fp8) + VT projection (bf16) ----------------
// ids [0,1024): fp8 Q/K proj. xcd=id%8, t=id/8, m=t%4, gg=xcd+8*(t/4): y=gg%128, z=gg/128
// ids [1024,1536): VT[d,kv] = sum_k WvT[d,k]*value[kv,k]; z=id2%8, ym=(id2/8)%4, xn=(id2/8)/4
__global__ __launch_bounds__(256) void proj_gemm(
    const u8* __restrict__ query8, const u8* __restrict__ key8,
    const u8* __restrict__ WqT8, const u8* __restrict__ WkT8,
    u8* __restrict__ Qb8, u8* __restrict__ Kb8,
    const bf16* __restrict__ valueb, const bf16* __restrict__ WvT,
    bf16* __restrict__ VT, u8* __restrict__ VT8)
{
    __shared__ __align__(16) u8 smem[32768];
    const int tid = threadIdx.x;
    const int wave = tid >> 6, lane = tid & 63;
    const int wm = (wave & 1) * 64, wn = (wave >> 1) * 64;
    const int lm = lane & 15, quad = lane >> 4;
    const int id = blockIdx.x;

    floatx4_t acc[4][4];
#pragma unroll
    for (int i = 0; i < 4; ++i)
#pragma unroll
        for (int j = 0; j < 4; ++j) acc[i][j] = 0.0f;

    if (id < 1024) {
        const int xcd = id & 7, t = id >> 3, m = t & 3;
        const int gg = xcd + 8 * (t >> 2);
        const int y = gg & 127, z = gg >> 7;
        const u8* Ap = (z ? key8 : query8) + (long long)y * 128 * DIN;
        const u8* Bp = (z ? WkT8 : WqT8) + (long long)m * 128 * DIN;
        gemm_mainloop_fp8(acc, Ap, Bp, DIN, DIN, DIN, smem, smem + 16384, wave, lane);
        u8* C = z ? Kb8 : Qb8;
#pragma unroll
        for (int i = 0; i < 4; ++i)
#pragma unroll
            for (int j = 0; j < 4; ++j) {
                const int row0 = y * 128 + wm + i * 16 + quad * 4;
                const int col = m * 128 + wn + j * 16 + lm;
#pragma unroll
                for (int r = 0; r < 4; ++r)
                    C[(long long)(row0 + r) * DOUT + swz_off(row0 + r, col)] = to_fp8(acc[i][j][r]);
            }
    } else {
        const int id2 = id - 1024;
        const int z = id2 & 7, r2 = id2 >> 3;
        const int ym = r2 & 3, xn = r2 >> 2;
        const bf16* Ap = WvT + (long long)ym * 128 * DIN;
        const bf16* Bp = valueb + (long long)z * (SKV * DIN) + (long long)xn * 128 * DIN;
        gemm_mainloop(acc, Ap, Bp, DIN, DIN, DIN, (bf16*)smem, (bf16*)(smem + 16384), wave, lane);
        u8* C = (u8*)(VT + (long long)z * (DOUT * SKV));
        u8* C8 = VT8 + (long long)z * (DOUT * SKV);
#pragma unroll
        for (int i = 0; i < 4; ++i)
#pragma unroll
            for (int j = 0; j < 4; ++j) {
                const int row0 = ym * 128 + wm + i * 16 + quad * 4;
                const int col = xn * 128 + wn + j * 16 + lm;
#pragma unroll
                for (int r = 0; r < 4; ++r) {
                    float v = acc[i][j][r];
                    const int rr = row0 + r;
                    *(bf16*)&C[(long long)rr * (SKV * 2) + swz_off(rr, col * 2)] = (bf16)v;
                    C8[(long long)rr * SKV + swz_off(rr, col)] = to_fp8(v);
                }
            }
    }
}

// ---------------- G split-K2: G32h = (Woff @ V)^T partial, bf16 path ----------------
// grid 256: z=id%8, h=(id>>3)&1, x=(id>>4)&3, y=(id>>6)&3
__global__ __launch_bounds__(256) void g_gemm(
    const bf16* __restrict__ VT, const bf16* __restrict__ Woffb,
    float* __restrict__ G32a, float* __restrict__ G32b)
{
    __shared__ __align__(16) u8 smem[32768];
    const int tid = threadIdx.x;
    const int wave = tid >> 6, lane = tid & 63;
    const int id = blockIdx.x;
    const int z = id & 7, h = (id >> 3) & 1, x = (id >> 4) & 3, y = (id >> 6) & 3;

    floatx4_t acc[4][4];
#pragma unroll
    for (int i = 0; i < 4; ++i)
#pragma unroll
        for (int j = 0; j < 4; ++j) acc[i][j] = 0.0f;

    const bf16* Ap = VT + (long long)z * (DOUT * SKV) + (long long)y * 128 * SKV + h * 1024;
    const bf16* Bp = Woffb + (long long)x * 128 * SKV + h * 1024;
    gemm_mainloop(acc, Ap, Bp, SKV, SKV, 1024, (bf16*)smem, (bf16*)(smem + 16384), wave, lane);

    const int wm = (wave & 1) * 64, wn = (wave >> 1) * 64;
    const int lm = lane & 15, quad = lane >> 4;
    float* C = (h ? G32b : G32a) + (long long)z * (DOUT * DIN);
#pragma unroll
    for (int i = 0; i < 4; ++i)
#pragma unroll
        for (int j = 0; j < 4; ++j) {
            const int row0 = y * 128 + wm + i * 16 + quad * 4;
            const int col = x * 128 + wn + j * 16 + lm;
#pragma unroll
            for (int r = 0; r < 4; ++r)
                C[(long long)(row0 + r) * DIN + col] = acc[i][j][r];
        }
}

// ---------------- S-GEMM fp8 + exp epilogue + row sums; ids>=2048 convert G32->Gb ----------------
// grid 2112: s-blocks: z=id%8, x=(id/8)%16, y=(id/8)/16
__global__ __launch_bounds__(256) void s_gemm_exp(
    const u8* __restrict__ Qb8, const u8* __restrict__ Kb8,
    u8* __restrict__ expS8, float* __restrict__ l,
    const float* __restrict__ G32a, const float* __restrict__ G32b,
    bf16* __restrict__ Gb)
{
    __shared__ __align__(16) u8 smem[32768];
    const int tid = threadIdx.x;
    const int id = blockIdx.x;
    if (id >= 2048) {
        // convert G32a+G32b -> Gb (swizzled, rows = 512 bf16 = 1024 B)
        const int base = (id - 2048) * 256 + tid;
        const float4* A4 = (const float4*)G32a;
        const float4* B4 = (const float4*)G32b;
        u8* O = (u8*)Gb;
#pragma unroll 4
        for (int t = 0; t < 32; ++t) {
            const int idx = base + t * 16384;
            float4 a = A4[idx], b = B4[idx];
            bf16x4_t o = { (bf16)(a.x + b.x), (bf16)(a.y + b.y),
                           (bf16)(a.z + b.z), (bf16)(a.w + b.w) };
            const long long boff = (long long)idx * 8;
            const int row = (int)(boff >> 10);
            const int cb = (int)(boff & 1023);
            *(bf16x4_t*)&O[((long long)row << 10) + swz_off(row, cb)] = o;
        }
        return;
    }
    const int wave = tid >> 6, lane = tid & 63;
    const int z = id & 7, x = (id >> 3) & 15, y = (id >> 3) >> 4;

    floatx4_t acc[4][4];
#pragma unroll
    for (int i = 0; i < 4; ++i)
#pragma unroll
        for (int j = 0; j < 4; ++j) acc[i][j] = 0.0f;

    const u8* Ap = Qb8 + ((long long)z * SQ + (long long)y * 128) * DOUT;
    const u8* Bp = Kb8 + ((long long)z * SKV + (long long)x * 128) * DOUT;
    gemm_mainloop_fp8(acc, Ap, Bp, DOUT, DOUT, DOUT, smem, smem + 16384, wave, lane);

    const int wm = (wave & 1) * 64, wn = (wave >> 1) * 64;
    const int lm = lane & 15, quad = lane >> 4;
    u8* C = expS8 + (long long)z * SQ * SKV;
    const long long grow0 = (long long)z * SQ + (long long)y * 128;
#pragma unroll
    for (int i = 0; i < 4; ++i) {
        float rs[4] = {0.f, 0.f, 0.f, 0.f};
#pragma unroll
        for (int j = 0; j < 4; ++j) {
            const int row0 = y * 128 + wm + i * 16 + quad * 4;
            const int col = x * 128 + wn + j * 16 + lm;
#pragma unroll
            for (int r = 0; r < 4; ++r) {
                float e = __expf(acc[i][j][r] * SCORE_SCALE);
                rs[r] += e;
                C[(long long)(row0 + r) * SKV + swz_off(row0 + r, col)] = to_fp8(e * P_STORE_SCALE);
            }
        }
#pragma unroll
        for (int r = 0; r < 4; ++r) {
            float v = rs[r];
            v += __shfl_xor(v, 1, 64);
            v += __shfl_xor(v, 2, 64);
            v += __shfl_xor(v, 4, 64);
            v += __shfl_xor(v, 8, 64);
            if (lm == 0)
                atomicAdd(&l[grow0 + wm + i * 16 + quad * 4 + r], v);
        }
    }
}

// ---------------- out = (expS8 @ V8)*16/l + offset @ G ----------------
// grid 512: z=id%8, x=(id/8)%4, y=(id/8)/4
__global__ __launch_bounds__(256) void out_gemm(
    const u8* __restrict__ expS8, const u8* __restrict__ VT8,
    const bf16* __restrict__ offb, const bf16* __restrict__ Gb,
    const float* __restrict__ l, float* __restrict__ out)
{
    __shared__ __align__(16) u8 smem[32768];
    const int tid = threadIdx.x;
    const int wave = tid >> 6, lane = tid & 63;
    const int id = blockIdx.x;
    const int z = id & 7, x = (id >> 3) & 3, y = (id >> 3) >> 2;

    floatx4_t acc[4][4];
#pragma unroll
    for (int i = 0; i < 4; ++i)
#pragma unroll
        for (int j = 0; j < 4; ++j) acc[i][j] = 0.0f;

    // pass 1 (fp8): expS8 @ VT8^T, K = SKV
    {
        const u8* Ap = expS8 + (long long)z * SQ * SKV + (long long)y * 128 * SKV;
        const u8* Bp = VT8 + (long long)z * DOUT * SKV + (long long)x * 128 * SKV;
        gemm_mainloop_fp8(acc, Ap, Bp, SKV, SKV, SKV, smem, smem + 16384, wave, lane);
    }

    const int wm = (wave & 1) * 64, wn = (wave >> 1) * 64;
    const int lm = lane & 15, quad = lane >> 4;
    const long long grow0 = (long long)z * SQ + (long long)y * 128;

    // scale by 16/l (undo P_STORE_SCALE, normalize softmax)
#pragma unroll
    for (int i = 0; i < 4; ++i)
#pragma unroll
        for (int r = 0; r < 4; ++r) {
            const float inv = P_UNDO_SCALE / l[grow0 + wm + i * 16 + quad * 4 + r];
#pragma unroll
            for (int j = 0; j < 4; ++j) acc[i][j][r] *= inv;
        }

    // pass 2 (bf16): offset @ G, K = DIN
    {
        const bf16* Ap = offb + grow0 * DIN;
        const bf16* Bp = Gb + (long long)z * DOUT * DIN + (long long)x * 128 * DIN;
        gemm_mainloop(acc, Ap, Bp, DIN, DIN, DIN, (bf16*)smem, (bf16*)(smem + 16384), wave, lane);
    }

#pragma unroll
    for (int i = 0; i < 4; ++i)
#pragma unroll
        for (int j = 0; j < 4; ++j) {
            const long long row0 = grow0 + wm + i * 16 + quad * 4;
            const int col = x * 128 + wn + j * 16 + lm;
#pragma unroll
            for (int r = 0; r < 4; ++r)
                out[(row0 + r) * DOUT + col] = acc[i][j][r];
        }
}

extern "C" void kernel_launch(void* const* d_in, const int* in_sizes, int n_in,
                              void* d_out, int out_size, void* d_ws, size_t ws_size,
                              hipStream_t stream) {
    const float* query = (const float*)d_in[0];
    const float* key_ = (const float*)d_in[1];
    const float* value = (const float*)d_in[2];
    const float* offset = (const float*)d_in[3];
    const float* Wq = (const float*)d_in[4];
    const float* Wk = (const float*)d_in[5];
    const float* Wv = (const float*)d_in[6];
    const float* Woff = (const float*)d_in[7];
    float* out = (float*)d_out;

    char* ws = (char*)d_ws;
    const long long NE = (long long)NB * SQ * DIN;  // 8,388,608
    const long long MB = 1048576;

    u8* query8   = (u8*)(ws + 0 * MB);     // 8 MB, fp8 swz
    u8* key8     = (u8*)(ws + 8 * MB);     // 8 MB
    bf16* valueb = (bf16*)(ws + 16 * MB);  // 16 MB, bf16 swz
    bf16* offsetb= (bf16*)(ws + 32 * MB);  // 16 MB, bf16 swz
    u8* Qb8      = (u8*)(ws + 48 * MB);    // 8 MB
    u8* Kb8      = (u8*)(ws + 56 * MB);    // 8 MB
    bf16* VT     = (bf16*)(ws + 64 * MB);  // 16 MB, bf16 swz
    u8* VT8      = (u8*)(ws + 80 * MB);    // 8 MB
    float* G32a  = (float*)(ws + 88 * MB); // 8 MB
    float* G32b  = (float*)(ws + 96 * MB); // 8 MB
    bf16* Gb     = (bf16*)(ws + 104 * MB); // 4 MB, bf16 swz
    u8* WqT8     = (u8*)(ws + 108 * MB);            // 256 KB
    u8* WkT8     = (u8*)(ws + 108 * MB + 262144);   // 256 KB
    bf16* WvT    = (bf16*)(ws + 108 * MB + 524288); // 512 KB, bf16 swz
    bf16* Woffb  = (bf16*)(ws + 109 * MB);          // 2 MB, bf16 swz
    float* lbuf  = (float*)(ws + 111 * MB);         // 64 KB
    u8* expS8    = (u8*)(ws + 112 * MB);   // 32 MB
    // total 144 MB

    // 1. casts (query/key fp8+swz, value/offset/Woff bf16+swz) + zero l
    CastArgs ca;
    ca.src[0] = query;  ca.dst[0] = query8;  ca.n4[0] = (int)(NE / 4); ca.mode[0] = 1; ca.rowshift[0] = 0;
    ca.src[1] = key_;   ca.dst[1] = key8;    ca.n4[1] = (int)(NE / 4); ca.mode[1] = 1; ca.rowshift[1] = 0;
    ca.src[2] = value;  ca.dst[2] = valueb;  ca.n4[2] = (int)(NE / 4); ca.mode[2] = 0; ca.rowshift[2] = 10;
    ca.src[3] = offset; ca.dst[3] = offsetb; ca.n4[3] = (int)(NE / 4); ca.mode[3] = 0; ca.rowshift[3] = 10;
    ca.src[4] = Woff;   ca.dst[4] = Woffb;   ca.n4[4] = (DIN * SKV) / 4; ca.mode[4] = 0; ca.rowshift[4] = 12;
    ca.src[5] = nullptr; ca.dst[5] = lbuf;   ca.n4[5] = (NB * SQ) / 4; ca.mode[5] = 2; ca.rowshift[5] = 0;
    cast_many<<<dim3(2048, 1, 6), 256, 0, stream>>>(ca);

    // 2. weight transposes: Wq,Wk -> fp8 swz x4; Wv -> bf16 swz
    TWArgs tw;
    tw.src[0] = Wq; tw.src[1] = Wk; tw.src[2] = Wv;
    tw.dst[0] = WqT8; tw.dst[1] = WkT8; tw.dst[2] = WvT;
    transpose_w<<<dim3(16, 16, 3), dim3(32, 8), 0, stream>>>(tw);

    // 3. Q,K projections (fp8) + VT projection (bf16, also writes VT8)
    proj_gemm<<<dim3(1536), 256, 0, stream>>>(query8, key8, WqT8, WkT8, Qb8, Kb8,
                                              valueb, WvT, VT, VT8);

    // 4. G = (Woff @ V)^T, split-K2 into two fp32 buffers
    g_gemm<<<dim3(256), 256, 0, stream>>>(VT, Woffb, G32a, G32b);

    // 5. expS8 = exp(scores)/16 (fp8) + row sums l; tail blocks convert G32 -> Gb
    s_gemm_exp<<<dim3(2112), 256, 0, stream>>>(Qb8, Kb8, expS8, lbuf, G32a, G32b, Gb);

    // 6. out = (expS8 @ V8)*16/l + offset @ G
    out_gemm<<<dim3(512), 256, 0, stream>>>(expS8, VT8, offsetb, Gb, lbuf, out);
}